// Round 8
// baseline (193.051 us; speedup 1.0000x reference)
//
#include <hip/hip_runtime.h>
#include <hip/hip_bf16.h>
#include <math.h>
#include <stdint.h>

// RandomProjectionQuantizer — bf16 MFMA filter + exact fp32 top-8 rescore.
//   mel [32,80,4000] f32, proj [2,80,64] f32, codebooks [2,1024,64] f32
//   codes[c,b,t] = argmax_k ( (mel[b,:,t] @ proj[c]) . cb[c,k,:]/||cb[c,k]|| )
//
// R8 vs R7 (proven, 168us): LDS 33280->29696 -> 5 blocks/CU (20 waves):
//   KT 64->32 (cbuf 2x4KB, 1 uint4/thread staging, 32 tiles);
//   cand stored TRANSPOSED candT[16][64][2] = 8192 B (exactly the dead cbuf
//   region; merge reads lane-stride 8B = conflict-free);
//   scv/sck padded [64][9] after PL. Filter math/swizzle/MFMA mapping/top-2/
//   top-8/rescore semantics unchanged. bfi-form packing (1 VALU less/reg).

#define B      32
#define NMELS  80
#define TSTEPS 4000
#define NCB    2
#define KCB    1024
#define DDIM   64
#define TPB    256
#define TM     64            // t's per block (16 per wave)
#define KT     32            // codebook rows per LDS tile (4 KB bf16)
#define NKT    (KCB / KT)    // 32 tiles
#define PPAD   66            // P row stride (floats) — proven

typedef short bf16x8 __attribute__((ext_vector_type(8)));
typedef float f32x4  __attribute__((ext_vector_type(4)));

#define WS_CB_OFF   8192                         // bytes: invn table first
#define WS_NEEDED   (8192 + NCB*KCB*DDIM*2)      // 270336 (proven fits, R4)

static __device__ __forceinline__ uint32_t bits(float f) {
    return __builtin_bit_cast(uint32_t, f);
}
static __device__ __forceinline__ float fbits(uint32_t u) {
    return __builtin_bit_cast(float, u);
}
// round-to-nearest-even f32 -> bf16 (returns low 16 bits)
static __device__ __forceinline__ uint32_t rne16(uint32_t u) {
    return (u + 0x7FFFu + ((u >> 16) & 1u)) >> 16;
}

// ---------------------------------------------------------------- prep ----
__global__ __launch_bounds__(TPB) void rpq_prep(const float* __restrict__ cb,
                                                float* __restrict__ ws)
{
    const int idx = blockIdx.x * TPB + threadIdx.x;
    if (idx >= NCB * KCB) return;

    const float4* row = (const float4*)(cb + (size_t)idx * DDIM);
    float4 v[16];
    float ss = 0.f;
    #pragma unroll
    for (int i = 0; i < 16; ++i) {
        v[i] = row[i];
        ss += v[i].x*v[i].x + v[i].y*v[i].y + v[i].z*v[i].z + v[i].w*v[i].w;
    }
    const float inv = 1.0f / fmaxf(sqrtf(ss), 1e-12f);
    ws[idx] = inv;

    uint32_t dw[32];
    #pragma unroll
    for (int i = 0; i < 16; ++i) {
        dw[2*i]   = rne16(bits(v[i].x * inv)) | (rne16(bits(v[i].y * inv)) << 16);
        dw[2*i+1] = rne16(bits(v[i].z * inv)) | (rne16(bits(v[i].w * inv)) << 16);
    }
    uint4* dst = (uint4*)((char*)ws + WS_CB_OFF + (size_t)idx * 128);
    #pragma unroll
    for (int i = 0; i < 8; ++i)
        dst[i] = make_uint4(dw[4*i], dw[4*i+1], dw[4*i+2], dw[4*i+3]);
}

// ---------------------------------------------------------------- main ----
__global__ __launch_bounds__(TPB, 5) void rpq_main(
    const float* __restrict__ mel,
    const float* __restrict__ proj,
    const float* __restrict__ cb,
    const float* __restrict__ ws,
    int* __restrict__ out)
{
    const int tid  = threadIdx.x;
    const int b    = blockIdx.y;
    const int c    = blockIdx.z;
    const int t0   = blockIdx.x * TM;

    const int l    = tid & 63;
    const int wid  = tid >> 6;      // wave 0..3
    const int lrow = l & 15;        // A/B row-col within 16x16
    const int lgrp = l >> 4;        // k-octet group 0..3

    // projS: phase-1 only. cbuf/PL written strictly after S2.
    // candT aliases cbuf — written strictly after the filter's final barrier.
    __shared__ union __align__(16) {
        float projS[NMELS * DDIM];              // 20480 B
        struct {
            union {
                char     cbuf[2][KT * 128];     // 8192 B (bf16 dbuf, swizzled)
                uint32_t candT[16][TM][2];      // 8192 B (transposed top-2)
            } a;
            float PL[TM * PPAD];                // 16896 B
            float scv[TM][9];                   // 2304 B (pad 9: conflict-free)
            int   sck[TM][9];                   // 2304 B
        } p2;
    } U;                                        // total 29696 B

    const char*  wscb   = (const char*)ws + WS_CB_OFF + (size_t)c * (KCB * 128);
    const float* invn_g = ws + (size_t)c * KCB;

    // ---- stage proj[c] into LDS ----
    {
        const float4* src = (const float4*)(proj + (size_t)c * NMELS * DDIM);
        float4* dst = (float4*)U.projS;
        for (int i = tid; i < NMELS * DDIM / 4; i += TPB) dst[i] = src[i];
    }
    __syncthreads();                                  // S1

    // ---- issue tile-0 staging load early (1 uint4/thread, KT=32 tile) ----
    const int srow = tid >> 3;     // staging row 0..31
    const int sq   = tid & 7;      // 16-byte slot in 128B row
    uint4 g0;
    g0 = *(const uint4*)(wscb + (size_t)tid * 16);    // == srow*128 + sq*16

    // ---- phase 1: P[t][d]; thread = (tq = tid&15 -> 4 t's, dg = tid>>4 -> 4 d's)
    {
        const int tq = tid & 15;
        const int dg = tid >> 4;
        const int tbase  = t0 + tq * 4;
        const int tb_c   = (tbase <= TSTEPS - 4) ? tbase : (TSTEPS - 4); // clamp
        const float* mp  = mel + (size_t)b * NMELS * TSTEPS + tb_c;

        float Pa[4][4];
        #pragma unroll
        for (int i = 0; i < 4; ++i)
            #pragma unroll
            for (int j = 0; j < 4; ++j) Pa[i][j] = 0.f;

        for (int n = 0; n < NMELS; ++n) {
            const float4 m4 = *(const float4*)(mp + (size_t)n * TSTEPS);
            const float4 w  = *(const float4*)&U.projS[n * DDIM + dg * 4];
            Pa[0][0] = fmaf(m4.x, w.x, Pa[0][0]); Pa[0][1] = fmaf(m4.x, w.y, Pa[0][1]);
            Pa[0][2] = fmaf(m4.x, w.z, Pa[0][2]); Pa[0][3] = fmaf(m4.x, w.w, Pa[0][3]);
            Pa[1][0] = fmaf(m4.y, w.x, Pa[1][0]); Pa[1][1] = fmaf(m4.y, w.y, Pa[1][1]);
            Pa[1][2] = fmaf(m4.y, w.z, Pa[1][2]); Pa[1][3] = fmaf(m4.y, w.w, Pa[1][3]);
            Pa[2][0] = fmaf(m4.z, w.x, Pa[2][0]); Pa[2][1] = fmaf(m4.z, w.y, Pa[2][1]);
            Pa[2][2] = fmaf(m4.z, w.z, Pa[2][2]); Pa[2][3] = fmaf(m4.z, w.w, Pa[2][3]);
            Pa[3][0] = fmaf(m4.w, w.x, Pa[3][0]); Pa[3][1] = fmaf(m4.w, w.y, Pa[3][1]);
            Pa[3][2] = fmaf(m4.w, w.z, Pa[3][2]); Pa[3][3] = fmaf(m4.w, w.w, Pa[3][3]);
        }
        __syncthreads();                              // S2: projS reads done

        #pragma unroll
        for (int i = 0; i < 4; ++i)
            *(float4*)&U.p2.PL[(tq * 4 + i) * PPAD + dg * 4] =
                make_float4(Pa[i][0], Pa[i][1], Pa[i][2], Pa[i][3]);
    }

    // ---- write tile 0 (XOR-swizzled rows, proven addressing) ----
    {
        const int xw = (srow & 7) << 4;
        *(uint4*)(&U.p2.a.cbuf[0][srow * 128] + ((sq * 16) ^ xw)) = g0;
    }
    __syncthreads();                                  // S3: PL + tile0 ready

    // ---- A fragments (bf16 RNE) from PL ----
    bf16x8 A0, A1;
    {
        const float* pr = &U.p2.PL[((wid << 4) + lrow) * PPAD];
        #pragma unroll
        for (int i = 0; i < 8; ++i) {
            A0[i] = (short)rne16(bits(pr[lgrp * 8 + i]));        // d 0..31
            A1[i] = (short)rne16(bits(pr[32 + lgrp * 8 + i]));   // d 32..63
        }
    }

    // ---- filter loop over 32 tiles (pre-normalized sims) ----
    float m1[4], m2[4];
    #pragma unroll
    for (int r = 0; r < 4; ++r) { m1[r] = -INFINITY; m2[r] = -INFINITY; }
    uint32_t idxv = (uint32_t)(1023 - lrow);  // payload = 1023 - k

    const int xr  = (lrow & 7) << 4;
    const int bo0 = (lgrp * 16) ^ xr;
    const int bo1 = (64 + lgrp * 16) ^ xr;

    for (int kt = 0; kt < NKT; ++kt) {
        const int cur = kt & 1;
        if (kt + 1 < NKT) {   // issue next-tile staging load
            g0 = *(const uint4*)(wscb + (size_t)(kt + 1) * (KT * 128)
                                 + (size_t)tid * 16);
        }
        const char* buf = U.p2.a.cbuf[cur];
        #pragma unroll
        for (int s = 0; s < 2; ++s) {
            const char* rowp = buf + (s * 16 + lrow) * 128;
            bf16x8 B0 = *(const bf16x8*)(rowp + bo0);
            bf16x8 B1 = *(const bf16x8*)(rowp + bo1);
            f32x4 acc = {0.f, 0.f, 0.f, 0.f};
            acc = __builtin_amdgcn_mfma_f32_16x16x32_bf16(A0, B0, acc, 0, 0, 0);
            acc = __builtin_amdgcn_mfma_f32_16x16x32_bf16(A1, B1, acc, 0, 0, 0);
            #pragma unroll
            for (int r = 0; r < 4; ++r) {
                // canonical BFI pattern: (x & M) | (idx & ~M) -> v_bfi_b32
                const float pf = fbits((bits(acc[r]) & 0xFFFFFC00u)
                                     | (idxv & 0x3FFu));
                m2[r] = __builtin_amdgcn_fmed3f(pf, m1[r], m2[r]);
                m1[r] = fmaxf(pf, m1[r]);
            }
            idxv -= 16u;
        }
        if (kt + 1 < NKT) {
            const int xw = (srow & 7) << 4;
            *(uint4*)(&U.p2.a.cbuf[cur ^ 1][srow * 128] + ((sq * 16) ^ xw)) = g0;
        }
        __syncthreads();
    }
    // cbuf is dead from here -> candT may alias it.

    // ---- per-lane top-2 -> candT[lane][t]; C row t = wid*16+lgrp*4+r (m89) ----
    #pragma unroll
    for (int r = 0; r < 4; ++r) {
        const int trow = (wid << 4) + (lgrp << 2) + r;
        U.p2.a.candT[lrow][trow][0] = bits(m1[r]);
        U.p2.a.candT[lrow][trow][1] = bits(m2[r]);
    }
    __syncthreads();                                  // S4

    // ---- merge top-8 per t (4 threads/t redundantly), rescore 2 each ----
    {
        const int t = tid & 63;
        const int j = wid;
        float c1 = -INFINITY, c2 = -INFINITY, c3 = -INFINITY, c4 = -INFINITY;
        float c5 = -INFINITY, c6 = -INFINITY, c7 = -INFINITY, c8 = -INFINITY;
        for (int i = 0; i < 16; ++i) {
            const uint2 pv2 = *(const uint2*)&U.p2.a.candT[i][t][0];
            #pragma unroll
            for (int jj = 0; jj < 2; ++jj) {
                const float p = fbits(jj ? pv2.y : pv2.x);
                c8 = fmaxf(fminf(p, c7), c8);
                c7 = fmaxf(fminf(p, c6), c7);
                c6 = fmaxf(fminf(p, c5), c6);
                c5 = fmaxf(fminf(p, c4), c5);
                c4 = fmaxf(fminf(p, c3), c4);
                c3 = fmaxf(fminf(p, c2), c3);
                c2 = fmaxf(fminf(p, c1), c2);
                c1 = fmaxf(p, c1);
            }
        }
        const float sel0 = (j == 0) ? c1 : (j == 1) ? c3 : (j == 2) ? c5 : c7;
        const float sel1 = (j == 0) ? c2 : (j == 1) ? c4 : (j == 2) ? c6 : c8;
        const float* pr  = &U.p2.PL[t * PPAD];
        const float* cbc = cb + (size_t)c * KCB * DDIM;
        #pragma unroll
        for (int e = 0; e < 2; ++e) {
            const float sel = e ? sel1 : sel0;
            const int kj = 1023 - (int)(bits(sel) & 0x3FFu);
            const float* cbr = cbc + (size_t)kj * DDIM;
            float a0 = 0.f, a1 = 0.f, a2 = 0.f, a3 = 0.f;
            #pragma unroll
            for (int i = 0; i < 16; ++i) {
                float4 pv = *(const float4*)(pr + i * 4);
                float4 cv = *(const float4*)(cbr + i * 4);
                a0 = fmaf(pv.x, cv.x, a0); a1 = fmaf(pv.y, cv.y, a1);
                a2 = fmaf(pv.z, cv.z, a2); a3 = fmaf(pv.w, cv.w, a3);
            }
            U.p2.scv[t][2*j + e] = ((a0 + a1) + (a2 + a3)) * invn_g[kj];
            U.p2.sck[t][2*j + e] = kj;
        }
    }
    __syncthreads();                                  // S5

    if (tid < TM) {
        const int tg = t0 + tid;
        if (tg < TSTEPS) {
            float best = U.p2.scv[tid][0];
            int   bk   = U.p2.sck[tid][0];
            #pragma unroll
            for (int s2 = 1; s2 < 8; ++s2) {
                const float v = U.p2.scv[tid][s2];
                const int  kk = U.p2.sck[tid][s2];
                if (v > best || (v == best && kk < bk)) { best = v; bk = kk; }
            }
            out[((size_t)c * B + b) * TSTEPS + tg] = bk;
        }
    }
}

// ------------------------------------------------------------- fallback ----
__global__ __launch_bounds__(TPB, 2) void rpq_fallback(
    const float* __restrict__ mel, const float* __restrict__ proj,
    const float* __restrict__ cb, int* __restrict__ out)
{
    const int tid = threadIdx.x;
    const int b = blockIdx.y, c = blockIdx.z;
    const int t0 = blockIdx.x * (TPB * 2) + tid;
    const int t1 = t0 + TPB;
    const int tc0 = (t0 < TSTEPS) ? t0 : (TSTEPS - 1);
    const int tc1 = (t1 < TSTEPS) ? t1 : (TSTEPS - 1);

    __shared__ union { float projS[NMELS*DDIM]; float cbS[2][64*DDIM]; } sh;
    __shared__ float invn[KCB];
    const float* cbc = cb + (size_t)c * KCB * DDIM;
    {
        const float4* src = (const float4*)(proj + (size_t)c * NMELS * DDIM);
        float4* dst = (float4*)sh.projS;
        for (int i = tid; i < NMELS*DDIM/4; i += TPB) dst[i] = src[i];
    }
    for (int j = 0; j < KCB/TPB; ++j) {
        const int k = j*TPB + tid;
        const float4* r = (const float4*)(cbc + (size_t)k * DDIM);
        float s = 0.f;
        #pragma unroll
        for (int i = 0; i < DDIM/4; ++i) {
            float4 v = r[i]; s += v.x*v.x + v.y*v.y + v.z*v.z + v.w*v.w;
        }
        invn[k] = 1.0f / fmaxf(sqrtf(s), 1e-12f);
    }
    float4 r0, r1, r2, r3;
    { const float4* g = (const float4*)cbc;
      r0 = g[tid]; r1 = g[tid+256]; r2 = g[tid+512]; r3 = g[tid+768]; }
    __syncthreads();
    float P0[DDIM], P1[DDIM];
    #pragma unroll
    for (int d = 0; d < DDIM; ++d) { P0[d] = 0.f; P1[d] = 0.f; }
    const float* mp = mel + (size_t)b * NMELS * TSTEPS;
    for (int n = 0; n < NMELS; ++n) {
        const float m0 = mp[(size_t)n*TSTEPS + tc0];
        const float m1_ = mp[(size_t)n*TSTEPS + tc1];
        const float4* ps = (const float4*)(sh.projS + n*DDIM);
        #pragma unroll
        for (int i = 0; i < DDIM/4; ++i) {
            float4 v = ps[i];
            P0[4*i+0]=fmaf(m0,v.x,P0[4*i+0]); P0[4*i+1]=fmaf(m0,v.y,P0[4*i+1]);
            P0[4*i+2]=fmaf(m0,v.z,P0[4*i+2]); P0[4*i+3]=fmaf(m0,v.w,P0[4*i+3]);
            P1[4*i+0]=fmaf(m1_,v.x,P1[4*i+0]); P1[4*i+1]=fmaf(m1_,v.y,P1[4*i+1]);
            P1[4*i+2]=fmaf(m1_,v.z,P1[4*i+2]); P1[4*i+3]=fmaf(m1_,v.w,P1[4*i+3]);
        }
    }
    __syncthreads();
    { float4* dst = (float4*)sh.cbS[0];
      dst[tid]=r0; dst[tid+256]=r1; dst[tid+512]=r2; dst[tid+768]=r3; }
    { const float4* g = (const float4*)(cbc + (size_t)64*DDIM);
      r0=g[tid]; r1=g[tid+256]; r2=g[tid+512]; r3=g[tid+768]; }
    __syncthreads();
    float best0 = -INFINITY, best1 = -INFINITY; int bi0 = 0, bi1 = 0;
    for (int kt = 0; kt < KCB/64; ++kt) {
        const int cur = kt & 1;
        const float* base = sh.cbS[cur];
        const int kbase = kt * 64;
        #pragma unroll 2
        for (int kk = 0; kk < 64; ++kk) {
            const float4* row = (const float4*)(base + kk*DDIM);
            float a0=0,a1=0,a2=0,a3=0,b0=0,b1=0,b2=0,b3=0;
            #pragma unroll
            for (int i = 0; i < DDIM/4; ++i) {
                float4 v = row[i];
                a0=fmaf(P0[4*i+0],v.x,a0); a1=fmaf(P0[4*i+1],v.y,a1);
                a2=fmaf(P0[4*i+2],v.z,a2); a3=fmaf(P0[4*i+3],v.w,a3);
                b0=fmaf(P1[4*i+0],v.x,b0); b1=fmaf(P1[4*i+1],v.y,b1);
                b2=fmaf(P1[4*i+2],v.z,b2); b3=fmaf(P1[4*i+3],v.w,b3);
            }
            const int k = kbase + kk;
            const float w = invn[k];
            const float s0 = ((a0+a1)+(a2+a3))*w;
            const float s1 = ((b0+b1)+(b2+b3))*w;
            if (s0 > best0) { best0 = s0; bi0 = k; }
            if (s1 > best1) { best1 = s1; bi1 = k; }
        }
        if (kt + 1 < KCB/64) {
            float4* dst = (float4*)sh.cbS[cur ^ 1];
            dst[tid]=r0; dst[tid+256]=r1; dst[tid+512]=r2; dst[tid+768]=r3;
            if (kt + 2 < KCB/64) {
                const float4* g = (const float4*)(cbc + (size_t)(kt+2)*64*DDIM);
                r0=g[tid]; r1=g[tid+256]; r2=g[tid+512]; r3=g[tid+768];
            }
        }
        __syncthreads();
    }
    const size_t ob = ((size_t)c * B + b) * TSTEPS;
    if (t0 < TSTEPS) out[ob + t0] = bi0;
    if (t1 < TSTEPS) out[ob + t1] = bi1;
}

// --------------------------------------------------------------- launch ----
extern "C" void kernel_launch(void* const* d_in, const int* in_sizes, int n_in,
                              void* d_out, int out_size, void* d_ws, size_t ws_size,
                              hipStream_t stream) {
    const float* mel  = (const float*)d_in[0];
    const float* proj = (const float*)d_in[1];
    const float* cb   = (const float*)d_in[2];
    int* out = (int*)d_out;

    if (ws_size >= (size_t)WS_NEEDED) {   // proven true on this harness (R4)
        float* ws = (float*)d_ws;
        rpq_prep<<<dim3((NCB*KCB + TPB - 1)/TPB), dim3(TPB), 0, stream>>>(cb, ws);
        dim3 grid((TSTEPS + TM - 1) / TM, B, NCB);     // (63, 32, 2)
        rpq_main<<<grid, dim3(TPB), 0, stream>>>(mel, proj, cb, ws, out);
    } else {
        dim3 grid((TSTEPS + TPB*2 - 1) / (TPB*2), B, NCB);
        rpq_fallback<<<grid, dim3(TPB), 0, stream>>>(mel, proj, cb, out);
    }
}

// Round 9
// 177.863 us; speedup vs baseline: 1.0854x; 1.0854x over previous
//
#include <hip/hip_runtime.h>
#include <hip/hip_bf16.h>
#include <math.h>
#include <stdint.h>

// RandomProjectionQuantizer — bf16 MFMA filter + exact fp32 top-8 rescore.
//   mel [32,80,4000] f32, proj [2,80,64] f32, codebooks [2,1024,64] f32
//   codes[c,b,t] = argmax_k ( (mel[b,:,t] @ proj[c]) . cb[c,k,:]/||cb[c,k]|| )
//
// R9 vs R7 (proven, 168us; R8's (256,5) spilled -> reverted):
//   Filter re-partitioned: wave w owns k-quarter [w*256,(w+1)*256), ALL 64 t's
//   (A-frags for 4 t-blocks in regs). B-fragments stream DIRECTLY from the
//   L2-resident ws codebook (no LDS staging, no cbuf, no filter barriers).
//   Kills the 4x LDS B-read amplification + 16 staging barriers.
//   Per-(t,quarter) top-2 via 4-round __shfl_xor merge -> 8 cand/t ->
//   proven exact-fp32 rescore. Phase-1 / prep / rescore logic unchanged.

#define B      32
#define NMELS  80
#define TSTEPS 4000
#define NCB    2
#define KCB    1024
#define DDIM   64
#define TPB    256
#define TM     64            // t's per block
#define PPAD   66            // P row stride (floats) — proven

typedef short bf16x8 __attribute__((ext_vector_type(8)));
typedef float f32x4  __attribute__((ext_vector_type(4)));

#define WS_CB_OFF   8192                         // bytes: invn table first
#define WS_NEEDED   (8192 + NCB*KCB*DDIM*2)      // 270336 (proven fits, R4)

static __device__ __forceinline__ uint32_t bits(float f) {
    return __builtin_bit_cast(uint32_t, f);
}
static __device__ __forceinline__ float fbits(uint32_t u) {
    return __builtin_bit_cast(float, u);
}
// round-to-nearest-even f32 -> bf16 (returns low 16 bits)
static __device__ __forceinline__ uint32_t rne16(uint32_t u) {
    return (u + 0x7FFFu + ((u >> 16) & 1u)) >> 16;
}

// ---------------------------------------------------------------- prep ----
__global__ __launch_bounds__(TPB) void rpq_prep(const float* __restrict__ cb,
                                                float* __restrict__ ws)
{
    const int idx = blockIdx.x * TPB + threadIdx.x;
    if (idx >= NCB * KCB) return;

    const float4* row = (const float4*)(cb + (size_t)idx * DDIM);
    float4 v[16];
    float ss = 0.f;
    #pragma unroll
    for (int i = 0; i < 16; ++i) {
        v[i] = row[i];
        ss += v[i].x*v[i].x + v[i].y*v[i].y + v[i].z*v[i].z + v[i].w*v[i].w;
    }
    const float inv = 1.0f / fmaxf(sqrtf(ss), 1e-12f);
    ws[idx] = inv;

    uint32_t dw[32];
    #pragma unroll
    for (int i = 0; i < 16; ++i) {
        dw[2*i]   = rne16(bits(v[i].x * inv)) | (rne16(bits(v[i].y * inv)) << 16);
        dw[2*i+1] = rne16(bits(v[i].z * inv)) | (rne16(bits(v[i].w * inv)) << 16);
    }
    uint4* dst = (uint4*)((char*)ws + WS_CB_OFF + (size_t)idx * 128);
    #pragma unroll
    for (int i = 0; i < 8; ++i)
        dst[i] = make_uint4(dw[4*i], dw[4*i+1], dw[4*i+2], dw[4*i+3]);
}

// ---------------------------------------------------------------- main ----
__global__ __launch_bounds__(TPB, 4) void rpq_main(
    const float* __restrict__ mel,
    const float* __restrict__ proj,
    const float* __restrict__ cb,
    const float* __restrict__ ws,
    int* __restrict__ out)
{
    const int tid  = threadIdx.x;
    const int b    = blockIdx.y;
    const int c    = blockIdx.z;
    const int t0   = blockIdx.x * TM;

    const int l    = tid & 63;
    const int wid  = tid >> 6;      // wave 0..3 = k-quarter owner
    const int lrow = l & 15;        // A row / B col within 16x16
    const int lgrp = l >> 4;        // d-octet group 0..3

    // projS phase-1 only; PL/wcand/scv/sck written strictly after S2/S3.
    __shared__ union __align__(16) {
        float projS[NMELS * DDIM];              // 20480 B
        struct {
            float PL[TM * PPAD];                // 16896 B
            uint2 wcand[4][TM];                 // 2048 B (per-wave top-2 per t)
            float scv[TM][9];                   // 2304 B
            int   sck[TM][9];                   // 2304 B
        } p2;
    } U;                                        // total 23552 B

    const char*  wscb   = (const char*)ws + WS_CB_OFF + (size_t)c * (KCB * 128);
    const float* invn_g = ws + (size_t)c * KCB;

    // ---- stage proj[c] into LDS ----
    {
        const float4* src = (const float4*)(proj + (size_t)c * NMELS * DDIM);
        float4* dst = (float4*)U.projS;
        for (int i = tid; i < NMELS * DDIM / 4; i += TPB) dst[i] = src[i];
    }
    __syncthreads();                                  // S1

    // ---- phase 1 (R7-proven): thread = (tq = tid&15 -> 4 t's, dg = tid>>4) ----
    {
        const int tq = tid & 15;
        const int dg = tid >> 4;
        const int tbase  = t0 + tq * 4;
        const int tb_c   = (tbase <= TSTEPS - 4) ? tbase : (TSTEPS - 4);
        const float* mp  = mel + (size_t)b * NMELS * TSTEPS + tb_c;

        float Pa[4][4];
        #pragma unroll
        for (int i = 0; i < 4; ++i)
            #pragma unroll
            for (int j = 0; j < 4; ++j) Pa[i][j] = 0.f;

        for (int n = 0; n < NMELS; ++n) {
            const float4 m4 = *(const float4*)(mp + (size_t)n * TSTEPS);
            const float4 w  = *(const float4*)&U.projS[n * DDIM + dg * 4];
            Pa[0][0] = fmaf(m4.x, w.x, Pa[0][0]); Pa[0][1] = fmaf(m4.x, w.y, Pa[0][1]);
            Pa[0][2] = fmaf(m4.x, w.z, Pa[0][2]); Pa[0][3] = fmaf(m4.x, w.w, Pa[0][3]);
            Pa[1][0] = fmaf(m4.y, w.x, Pa[1][0]); Pa[1][1] = fmaf(m4.y, w.y, Pa[1][1]);
            Pa[1][2] = fmaf(m4.y, w.z, Pa[1][2]); Pa[1][3] = fmaf(m4.y, w.w, Pa[1][3]);
            Pa[2][0] = fmaf(m4.z, w.x, Pa[2][0]); Pa[2][1] = fmaf(m4.z, w.y, Pa[2][1]);
            Pa[2][2] = fmaf(m4.z, w.z, Pa[2][2]); Pa[2][3] = fmaf(m4.z, w.w, Pa[2][3]);
            Pa[3][0] = fmaf(m4.w, w.x, Pa[3][0]); Pa[3][1] = fmaf(m4.w, w.y, Pa[3][1]);
            Pa[3][2] = fmaf(m4.w, w.z, Pa[3][2]); Pa[3][3] = fmaf(m4.w, w.w, Pa[3][3]);
        }
        __syncthreads();                              // S2: projS reads done

        #pragma unroll
        for (int i = 0; i < 4; ++i)
            *(float4*)&U.p2.PL[(tq * 4 + i) * PPAD + dg * 4] =
                make_float4(Pa[i][0], Pa[i][1], Pa[i][2], Pa[i][3]);
    }
    __syncthreads();                                  // S3: PL ready

    // ---- A fragments (bf16 RNE) for ALL 4 t-blocks ----
    bf16x8 A0[4], A1[4];
    #pragma unroll
    for (int tb = 0; tb < 4; ++tb) {
        const float* pr = &U.p2.PL[(tb * 16 + lrow) * PPAD];
        #pragma unroll
        for (int i = 0; i < 8; ++i) {
            A0[tb][i] = (short)rne16(bits(pr[lgrp * 8 + i]));        // d 0..31
            A1[tb][i] = (short)rne16(bits(pr[32 + lgrp * 8 + i]));   // d 32..63
        }
    }

    // ---- filter: wave streams its k-quarter straight from L2 (no barriers) ----
    float m1[4][4], m2[4][4];
    #pragma unroll
    for (int tb = 0; tb < 4; ++tb)
        #pragma unroll
        for (int r = 0; r < 4; ++r) { m1[tb][r] = -INFINITY; m2[tb][r] = -INFINITY; }

    const char* qbase = wscb + (size_t)wid * (256 * 128);   // this wave's quarter
    const int lo0 = lrow * 128 + lgrp * 16;                  // d 0..31 bytes
    const int lo1 = lo0 + 64;                                // d 32..63 bytes
    uint32_t idxv = (uint32_t)(1023 - (wid << 8) - lrow);    // payload = 1023-k

    #pragma unroll 4
    for (int g = 0; g < 16; ++g) {                // 16 row-groups of 16 k
        const bf16x8 B0 = *(const bf16x8*)(qbase + g * 2048 + lo0);
        const bf16x8 B1 = *(const bf16x8*)(qbase + g * 2048 + lo1);
        #pragma unroll
        for (int tb = 0; tb < 4; ++tb) {
            f32x4 acc = {0.f, 0.f, 0.f, 0.f};
            acc = __builtin_amdgcn_mfma_f32_16x16x32_bf16(A0[tb], B0, acc, 0, 0, 0);
            acc = __builtin_amdgcn_mfma_f32_16x16x32_bf16(A1[tb], B1, acc, 0, 0, 0);
            #pragma unroll
            for (int r = 0; r < 4; ++r) {
                const float pf = fbits((bits(acc[r]) & 0xFFFFFC00u)
                                     | (idxv & 0x3FFu));
                m2[tb][r] = __builtin_amdgcn_fmed3f(pf, m1[tb][r], m2[tb][r]);
                m1[tb][r] = fmaxf(pf, m1[tb][r]);
            }
        }
        idxv -= 16u;
    }

    // ---- in-wave top-2 merge across the 16 lrow lanes (shfl butterfly) ----
    // C layout (m89): acc row t = tb*16 + lgrp*4 + r, col = k-within-group.
    #pragma unroll
    for (int tb = 0; tb < 4; ++tb) {
        #pragma unroll
        for (int r = 0; r < 4; ++r) {
            float a1 = m1[tb][r], a2 = m2[tb][r];
            #pragma unroll
            for (int m = 1; m <= 8; m <<= 1) {
                const float b1 = __shfl_xor(a1, m);
                const float b2 = __shfl_xor(a2, m);
                const float lo = fminf(a1, b1);
                a1 = fmaxf(a1, b1);
                a2 = fmaxf(lo, fmaxf(a2, b2));
            }
            if (lrow == 0)
                U.p2.wcand[wid][tb * 16 + (lgrp << 2) + r] =
                    make_uint2(bits(a1), bits(a2));
        }
    }
    __syncthreads();                                  // S4: wcand ready

    // ---- exact fp32 rescore: thread (t = tid&63, j = wid) does 2 of 8 ----
    {
        const int t = tid & 63;
        const int j = wid;
        const uint2 cd = U.p2.wcand[j][t];
        const float* pr  = &U.p2.PL[t * PPAD];
        const float* cbc = cb + (size_t)c * KCB * DDIM;
        #pragma unroll
        for (int e = 0; e < 2; ++e) {
            const uint32_t sv = e ? cd.y : cd.x;
            const int kj = 1023 - (int)(sv & 0x3FFu);
            const float* cbr = cbc + (size_t)kj * DDIM;
            float a0 = 0.f, a1 = 0.f, a2 = 0.f, a3 = 0.f;
            #pragma unroll
            for (int i = 0; i < 16; ++i) {
                float4 pv = *(const float4*)(pr + i * 4);
                float4 cv = *(const float4*)(cbr + i * 4);
                a0 = fmaf(pv.x, cv.x, a0); a1 = fmaf(pv.y, cv.y, a1);
                a2 = fmaf(pv.z, cv.z, a2); a3 = fmaf(pv.w, cv.w, a3);
            }
            U.p2.scv[t][2*j + e] = ((a0 + a1) + (a2 + a3)) * invn_g[kj];
            U.p2.sck[t][2*j + e] = kj;
        }
    }
    __syncthreads();                                  // S5

    if (tid < TM) {
        const int tg = t0 + tid;
        if (tg < TSTEPS) {
            float best = U.p2.scv[tid][0];
            int   bk   = U.p2.sck[tid][0];
            #pragma unroll
            for (int s2 = 1; s2 < 8; ++s2) {
                const float v = U.p2.scv[tid][s2];
                const int  kk = U.p2.sck[tid][s2];
                if (v > best || (v == best && kk < bk)) { best = v; bk = kk; }
            }
            out[((size_t)c * B + b) * TSTEPS + tg] = bk;
        }
    }
}

// ------------------------------------------------------------- fallback ----
__global__ __launch_bounds__(TPB, 2) void rpq_fallback(
    const float* __restrict__ mel, const float* __restrict__ proj,
    const float* __restrict__ cb, int* __restrict__ out)
{
    const int tid = threadIdx.x;
    const int b = blockIdx.y, c = blockIdx.z;
    const int t0 = blockIdx.x * (TPB * 2) + tid;
    const int t1 = t0 + TPB;
    const int tc0 = (t0 < TSTEPS) ? t0 : (TSTEPS - 1);
    const int tc1 = (t1 < TSTEPS) ? t1 : (TSTEPS - 1);

    __shared__ union { float projS[NMELS*DDIM]; float cbS[2][64*DDIM]; } sh;
    __shared__ float invn[KCB];
    const float* cbc = cb + (size_t)c * KCB * DDIM;
    {
        const float4* src = (const float4*)(proj + (size_t)c * NMELS * DDIM);
        float4* dst = (float4*)sh.projS;
        for (int i = tid; i < NMELS*DDIM/4; i += TPB) dst[i] = src[i];
    }
    for (int j = 0; j < KCB/TPB; ++j) {
        const int k = j*TPB + tid;
        const float4* r = (const float4*)(cbc + (size_t)k * DDIM);
        float s = 0.f;
        #pragma unroll
        for (int i = 0; i < DDIM/4; ++i) {
            float4 v = r[i]; s += v.x*v.x + v.y*v.y + v.z*v.z + v.w*v.w;
        }
        invn[k] = 1.0f / fmaxf(sqrtf(s), 1e-12f);
    }
    float4 r0, r1, r2, r3;
    { const float4* g = (const float4*)cbc;
      r0 = g[tid]; r1 = g[tid+256]; r2 = g[tid+512]; r3 = g[tid+768]; }
    __syncthreads();
    float P0[DDIM], P1[DDIM];
    #pragma unroll
    for (int d = 0; d < DDIM; ++d) { P0[d] = 0.f; P1[d] = 0.f; }
    const float* mp = mel + (size_t)b * NMELS * TSTEPS;
    for (int n = 0; n < NMELS; ++n) {
        const float m0 = mp[(size_t)n*TSTEPS + tc0];
        const float m1_ = mp[(size_t)n*TSTEPS + tc1];
        const float4* ps = (const float4*)(sh.projS + n*DDIM);
        #pragma unroll
        for (int i = 0; i < DDIM/4; ++i) {
            float4 v = ps[i];
            P0[4*i+0]=fmaf(m0,v.x,P0[4*i+0]); P0[4*i+1]=fmaf(m0,v.y,P0[4*i+1]);
            P0[4*i+2]=fmaf(m0,v.z,P0[4*i+2]); P0[4*i+3]=fmaf(m0,v.w,P0[4*i+3]);
            P1[4*i+0]=fmaf(m1_,v.x,P1[4*i+0]); P1[4*i+1]=fmaf(m1_,v.y,P1[4*i+1]);
            P1[4*i+2]=fmaf(m1_,v.z,P1[4*i+2]); P1[4*i+3]=fmaf(m1_,v.w,P1[4*i+3]);
        }
    }
    __syncthreads();
    { float4* dst = (float4*)sh.cbS[0];
      dst[tid]=r0; dst[tid+256]=r1; dst[tid+512]=r2; dst[tid+768]=r3; }
    { const float4* g = (const float4*)(cbc + (size_t)64*DDIM);
      r0=g[tid]; r1=g[tid+256]; r2=g[tid+512]; r3=g[tid+768]; }
    __syncthreads();
    float best0 = -INFINITY, best1 = -INFINITY; int bi0 = 0, bi1 = 0;
    for (int kt = 0; kt < KCB/64; ++kt) {
        const int cur = kt & 1;
        const float* base = sh.cbS[cur];
        const int kbase = kt * 64;
        #pragma unroll 2
        for (int kk = 0; kk < 64; ++kk) {
            const float4* row = (const float4*)(base + kk*DDIM);
            float a0=0,a1=0,a2=0,a3=0,b0=0,b1=0,b2=0,b3=0;
            #pragma unroll
            for (int i = 0; i < DDIM/4; ++i) {
                float4 v = row[i];
                a0=fmaf(P0[4*i+0],v.x,a0); a1=fmaf(P0[4*i+1],v.y,a1);
                a2=fmaf(P0[4*i+2],v.z,a2); a3=fmaf(P0[4*i+3],v.w,a3);
                b0=fmaf(P1[4*i+0],v.x,b0); b1=fmaf(P1[4*i+1],v.y,b1);
                b2=fmaf(P1[4*i+2],v.z,b2); b3=fmaf(P1[4*i+3],v.w,b3);
            }
            const int k = kbase + kk;
            const float w = invn[k];
            const float s0 = ((a0+a1)+(a2+a3))*w;
            const float s1 = ((b0+b1)+(b2+b3))*w;
            if (s0 > best0) { best0 = s0; bi0 = k; }
            if (s1 > best1) { best1 = s1; bi1 = k; }
        }
        if (kt + 1 < KCB/64) {
            float4* dst = (float4*)sh.cbS[cur ^ 1];
            dst[tid]=r0; dst[tid+256]=r1; dst[tid+512]=r2; dst[tid+768]=r3;
            if (kt + 2 < KCB/64) {
                const float4* g = (const float4*)(cbc + (size_t)(kt+2)*64*DDIM);
                r0=g[tid]; r1=g[tid+256]; r2=g[tid+512]; r3=g[tid+768];
            }
        }
        __syncthreads();
    }
    const size_t ob = ((size_t)c * B + b) * TSTEPS;
    if (t0 < TSTEPS) out[ob + t0] = bi0;
    if (t1 < TSTEPS) out[ob + t1] = bi1;
}

// --------------------------------------------------------------- launch ----
extern "C" void kernel_launch(void* const* d_in, const int* in_sizes, int n_in,
                              void* d_out, int out_size, void* d_ws, size_t ws_size,
                              hipStream_t stream) {
    const float* mel  = (const float*)d_in[0];
    const float* proj = (const float*)d_in[1];
    const float* cb   = (const float*)d_in[2];
    int* out = (int*)d_out;

    if (ws_size >= (size_t)WS_NEEDED) {   // proven true on this harness (R4)
        float* ws = (float*)d_ws;
        rpq_prep<<<dim3((NCB*KCB + TPB - 1)/TPB), dim3(TPB), 0, stream>>>(cb, ws);
        dim3 grid((TSTEPS + TM - 1) / TM, B, NCB);     // (63, 32, 2)
        rpq_main<<<grid, dim3(TPB), 0, stream>>>(mel, proj, cb, ws, out);
    } else {
        dim3 grid((TSTEPS + TPB*2 - 1) / (TPB*2), B, NCB);
        rpq_fallback<<<grid, dim3(TPB), 0, stream>>>(mel, proj, cb, out);
    }
}